// Round 3
// baseline (234.820 us; speedup 1.0000x reference)
//
#include <hip/hip_runtime.h>

// CircleLoss on MI355X: mean(log1p(exp(-64*(sim*(2*pos-1) - 0.35*64))))
// over the 8192x8192 cosine-sim Gram matrix.
//
// Plan:
//   k1: fused row-norm + bf16 hi/lo split  -> ws (e_hi, e_lo)
//   k2: upper-triangular 128x128 MFMA Gram tiles (3 MFMAs: hh + hl + lh
//       ~= fp32 precision; lo*lo term ~2^-18 rel, dropped),
//       fused softplus loss epilogue, per-block partial sums -> ws
//   k3: deterministic final reduction -> d_out[0]
//
// ws layout: [e_hi: N*D u16][e_lo: N*D u16][partials: NT*(NT+1)/2 float]
//            = 16.8 MB + 8.3 KB for N=8192, D=512.

typedef unsigned short u16;
typedef unsigned int u32;
typedef __attribute__((ext_vector_type(4))) float f32x4;
typedef __attribute__((ext_vector_type(8))) short bf16x8;
typedef __attribute__((ext_vector_type(8))) u16 u16x8;

#define AS1 __attribute__((address_space(1)))
#define AS3 __attribute__((address_space(3)))

__device__ __forceinline__ u16 bf16_rne(float x) {
  u32 u = __float_as_uint(x);
  u += 0x7FFFu + ((u >> 16) & 1u);
  return (u16)(u >> 16);
}

// One wave per row (D = 512 = 64 lanes * 8). Computes 1/max(||x||,eps),
// writes bf16 hi and lo parts of the normalized row.
__global__ __launch_bounds__(256) void norm_split_k(
    const float* __restrict__ emb, u16* __restrict__ ehi,
    u16* __restrict__ elo, int N, int D) {
  const int wid = threadIdx.x >> 6, lane = threadIdx.x & 63;
  const int row = blockIdx.x * 4 + wid;
  if (row >= N) return;
  const float* p = emb + (size_t)row * D + lane * 8;
  f32x4 a = *(const f32x4*)p;
  f32x4 b = *(const f32x4*)(p + 4);
  float ss = 0.f;
#pragma unroll
  for (int i = 0; i < 4; ++i) ss += a[i] * a[i] + b[i] * b[i];
#pragma unroll
  for (int o = 32; o >= 1; o >>= 1) ss += __shfl_xor(ss, o, 64);
  const float inv = 1.0f / fmaxf(sqrtf(ss), 1e-8f);
  u16x8 hv, lv;
#pragma unroll
  for (int i = 0; i < 8; ++i) {
    float x = (i < 4 ? a[i] : b[i - 4]) * inv;
    u32 u = __float_as_uint(x);
    u32 r = u + 0x7FFFu + ((u >> 16) & 1u);
    hv[i] = (u16)(r >> 16);
    float hif = __uint_as_float(r & 0xFFFF0000u);  // hi part back as f32 (exact)
    lv[i] = bf16_rne(x - hif);
  }
  size_t o = (size_t)row * D + lane * 8;
  *(u16x8*)(ehi + o) = hv;
  *(u16x8*)(elo + o) = lv;
}

// Upper-triangle tile (I<=J) Gram + loss. 256 threads = 4 waves, 2x2 wave grid,
// each wave owns a 64x64 quadrant = 4x4 fragments of 16x16, acc f32x4 each.
//
// LDS layout is fragment-ready lane-linear: frag q occupies 1024B; staging
// lane l writes its 16B at base + l*16 (global_load_lds semantics: uniform
// base + lane*size), gathered from global row (l&15), k-octet (l>>4). The
// fragment ds_read_b128 at byte offset lane*16 therefore hands lane l row
// (lane&15), k-octet (lane>>4) -- the m92-verified mfma_16x16x32 A/B
// fragment. Write-map == read-map, so LDS arrangement in between drops out;
// consecutive lanes hit consecutive 16B slots (no bank conflicts).
__global__ __launch_bounds__(256) void gram_loss_k(
    const u16* __restrict__ ehi, const u16* __restrict__ elo,
    const int* __restrict__ labels, float* __restrict__ partials,
    int N, int D, int NT) {
  __shared__ __attribute__((aligned(16))) u16 sAh[8 * 512];
  __shared__ __attribute__((aligned(16))) u16 sAl[8 * 512];
  __shared__ __attribute__((aligned(16))) u16 sBh[8 * 512];
  __shared__ __attribute__((aligned(16))) u16 sBl[8 * 512];
  __shared__ float swred[4];

  const int tid = threadIdx.x, wid = tid >> 6, lane = tid & 63;

  // blockIdx -> upper-triangular (I, J), I <= J
  int I = 0, rem = blockIdx.x, rl = NT;
  while (rem >= rl) { rem -= rl; ++I; --rl; }
  const int J = I + rem;
  const int i0 = I * 128, j0 = J * 128;

  // Staging: wave w stages one whole array (0:Ah 1:Al 2:Bh 3:Bl), 8 frags each.
  const u16* src = (wid & 1) ? elo : ehi;
  const int rbase = (wid < 2) ? i0 : j0;
  u16* ldsb = (wid == 0) ? sAh : (wid == 1) ? sAl : (wid == 2) ? sBh : sBl;

  u32 goff[8];
#pragma unroll
  for (int q = 0; q < 8; ++q)
    goff[q] = (u32)(rbase + q * 16 + (lane & 15)) * (u32)D + ((lane >> 4) * 8);

  const f32x4 z = {0.f, 0.f, 0.f, 0.f};
  f32x4 acc[4][4];
#pragma unroll
  for (int m = 0; m < 4; ++m)
#pragma unroll
    for (int n = 0; n < 4; ++n) acc[m][n] = z;

  const int wr = wid >> 1, wc = wid & 1;

  for (int kk = 0; kk < D; kk += 32) {
#pragma unroll
    for (int q = 0; q < 8; ++q)
      __builtin_amdgcn_global_load_lds((const AS1 void*)(src + goff[q] + kk),
                                       (AS3 void*)(ldsb + q * 512), 16, 0, 0);
    __syncthreads();  // compiler drains vmcnt before s_barrier -> tile ready

    bf16x8 ah[4], al[4], bh[4], bl[4];
#pragma unroll
    for (int m = 0; m < 4; ++m) {
      ah[m] = *(const bf16x8*)&sAh[(wr * 4 + m) * 512 + lane * 8];
      al[m] = *(const bf16x8*)&sAl[(wr * 4 + m) * 512 + lane * 8];
    }
#pragma unroll
    for (int n = 0; n < 4; ++n) {
      bh[n] = *(const bf16x8*)&sBh[(wc * 4 + n) * 512 + lane * 8];
      bl[n] = *(const bf16x8*)&sBl[(wc * 4 + n) * 512 + lane * 8];
    }
#pragma unroll
    for (int m = 0; m < 4; ++m)
#pragma unroll
      for (int n = 0; n < 4; ++n) {
        acc[m][n] = __builtin_amdgcn_mfma_f32_16x16x32_bf16(ah[m], bh[n], acc[m][n], 0, 0, 0);
        acc[m][n] = __builtin_amdgcn_mfma_f32_16x16x32_bf16(ah[m], bl[n], acc[m][n], 0, 0, 0);
        acc[m][n] = __builtin_amdgcn_mfma_f32_16x16x32_bf16(al[m], bh[n], acc[m][n], 0, 0, 0);
      }
    __syncthreads();  // all reads done before next stage overwrites
  }

  // Loss epilogue. C/D frag map (m89-verified): col = lane&15, row = (lane>>4)*4+reg.
  const float C0 = 64.0f * 0.35f;
  float lsum = 0.f;
  const int rb = i0 + wr * 64, cb = j0 + wc * 64;
#pragma unroll
  for (int m = 0; m < 4; ++m) {
    const int gi0 = rb + m * 16 + (lane >> 4) * 4;
#pragma unroll
    for (int n = 0; n < 4; ++n) {
      const int gj = cb + n * 16 + (lane & 15);
      const int lj = labels[gj];
#pragma unroll
      for (int r = 0; r < 4; ++r) {
        const int li = labels[gi0 + r];
        float s = acc[m][n][r];
        float sg = (li == lj) ? s : -s;
        float x = fmaf(-64.0f, sg, C0);           // -SCALE*(signed - MARGIN)
        float ax = fabsf(x);
        // log1p(exp(x)) = max(x,0) + log1p(exp(-|x|)); plain log fine: when
        // exp(-|x|) underflows vs 1 the term is negligible vs max(x,0).
        lsum += fmaxf(x, 0.f) + __logf(1.0f + __expf(-ax));
      }
    }
  }

#pragma unroll
  for (int o = 32; o >= 1; o >>= 1) lsum += __shfl_xor(lsum, o, 64);
  if (lane == 0) swred[wid] = lsum;
  __syncthreads();
  if (tid == 0) {
    float t = swred[0] + swred[1] + swred[2] + swred[3];
    partials[blockIdx.x] = (I == J) ? t : 2.0f * t;  // off-diag tiles count twice
  }
}

__global__ __launch_bounds__(256) void reduce_k(const float* __restrict__ partials,
                                                int n, float* __restrict__ out,
                                                double invNN) {
  double s = 0.0;
  for (int i = threadIdx.x; i < n; i += 256) s += (double)partials[i];
#pragma unroll
  for (int o = 32; o >= 1; o >>= 1) s += __shfl_xor(s, o, 64);
  __shared__ double sd[4];
  const int wid = threadIdx.x >> 6, lane = threadIdx.x & 63;
  if (lane == 0) sd[wid] = s;
  __syncthreads();
  if (threadIdx.x == 0) out[0] = (float)((sd[0] + sd[1] + sd[2] + sd[3]) * invNN);
}

extern "C" void kernel_launch(void* const* d_in, const int* in_sizes, int n_in,
                              void* d_out, int out_size, void* d_ws, size_t ws_size,
                              hipStream_t stream) {
  const float* emb = (const float*)d_in[0];
  const int* labels = (const int*)d_in[1];
  float* out = (float*)d_out;

  const int N = in_sizes[1];             // 8192
  const int D = in_sizes[0] / N;         // 512
  const int NT = N / 128;                // 64
  const int nTiles = NT * (NT + 1) / 2;  // 2080

  u16* ehi = (u16*)d_ws;
  u16* elo = ehi + (size_t)N * D;
  float* partials = (float*)(elo + (size_t)N * D);

  norm_split_k<<<N / 4, 256, 0, stream>>>(emb, ehi, elo, N, D);
  gram_loss_k<<<nTiles, 256, 0, stream>>>(ehi, elo, labels, partials, N, D, NT);
  reduce_k<<<1, 256, 0, stream>>>(partials, nTiles, out,
                                  1.0 / ((double)N * (double)N));
}

// Round 5
// 145.686 us; speedup vs baseline: 1.6118x; 1.6118x over previous
//
#include <hip/hip_runtime.h>

// CircleLoss on MI355X: mean(log1p(exp(-64*(sim*(2*pos-1) - 0.35*64))))
// over the 8192x8192 cosine-sim Gram matrix.
//
// R4 design (from R3 counters: latency/barrier-bound, MfmaUtil 23%, occ 19%):
//   k1: row-norm -> bf16 (single precision level; hi/lo split dropped --
//       mean-loss error analysis: ~1e-5 abs on ~22.4, random errors cancel)
//   k2: upper-tri 128x128 Gram tiles, ONE bf16 MFMA per fragment,
//       2-phase double-buffered prefetch (stage t+1 before compute t,
//       one __syncthreads per K-step), fused softplus epilogue
//   k3: deterministic final reduction
//
// ws: [e: N*D u16 bf16 (8.4 MB)][partials: NT*(NT+1)/2 float]

typedef unsigned short u16;
typedef unsigned int u32;
typedef __attribute__((ext_vector_type(4))) float f32x4;
typedef __attribute__((ext_vector_type(8))) short bf16x8;
typedef __attribute__((ext_vector_type(8))) u16 u16x8;

#define AS1 __attribute__((address_space(1)))
#define AS3 __attribute__((address_space(3)))

// One wave per row (D = 512 = 64 lanes * 8). 1/max(||x||,eps), bf16 RNE out.
__global__ __launch_bounds__(256) void norm_bf16_k(
    const float* __restrict__ emb, u16* __restrict__ e, int N, int D) {
  const int wid = threadIdx.x >> 6, lane = threadIdx.x & 63;
  const int row = blockIdx.x * 4 + wid;
  if (row >= N) return;
  const float* p = emb + (size_t)row * D + lane * 8;
  f32x4 a = *(const f32x4*)p;
  f32x4 b = *(const f32x4*)(p + 4);
  float ss = 0.f;
#pragma unroll
  for (int i = 0; i < 4; ++i) ss += a[i] * a[i] + b[i] * b[i];
#pragma unroll
  for (int o = 32; o >= 1; o >>= 1) ss += __shfl_xor(ss, o, 64);
  const float inv = 1.0f / fmaxf(sqrtf(ss), 1e-8f);
  u16x8 hv;
#pragma unroll
  for (int i = 0; i < 8; ++i) {
    float x = (i < 4 ? a[i] : b[i - 4]) * inv;
    u32 u = __float_as_uint(x);
    u += 0x7FFFu + ((u >> 16) & 1u);  // RNE to bf16
    hv[i] = (u16)(u >> 16);
  }
  *(u16x8*)(e + (size_t)row * D + lane * 8) = hv;
}

// Upper-tri tile (I<=J). 4 waves, 2x2 wave grid, 64x64 quadrant each =
// 4x4 fragments of mfma_f32_16x16x32_bf16.
//
// LDS: fragment-ready lane-linear (frag = 1024B, lane l holds 16B at l*16,
// gathered from global row l&15, k-octet l>>4). global_load_lds lane-linear
// write == ds_read_b128 fragment read => layout drops out; identical gather
// formula on A and B so any within-octet k-permutation cancels in A.B^T.
// Double-buffered (2x16.25KB): stage step t+1 into buf^1, compute buf, one
// __syncthreads per step (its vmcnt/lgkm drain is the fence: prefetch had
// the whole compute phase to land; buf^1 writes only start after barrier).
__global__ __launch_bounds__(256, 4) void gram_loss_k(
    const u16* __restrict__ e, const int* __restrict__ labels,
    float* __restrict__ partials, int N, int D, int NT) {
  __shared__ __attribute__((aligned(16))) u16 sA[2][8 * 512];
  __shared__ __attribute__((aligned(16))) u16 sB[2][8 * 512];
  __shared__ float swred[4];

  const int tid = threadIdx.x, wid = tid >> 6, lane = tid & 63;

  // blockIdx -> upper-triangular (I, J), I <= J
  int I = 0, rem = blockIdx.x, rl = NT;
  while (rem >= rl) { rem -= rl; ++I; --rl; }
  const int J = I + rem;
  const int i0 = I * 128, j0 = J * 128;

  // Staging: wave 0 -> A frags 0-3, wave 1 -> A frags 4-7,
  //          wave 2 -> B frags 0-3, wave 3 -> B frags 4-7.
  const int rbase = (wid < 2) ? i0 : j0;
  const int fq0 = (wid & 1) * 4;
  u32 goff[4];
#pragma unroll
  for (int q = 0; q < 4; ++q)
    goff[q] = (u32)(rbase + (fq0 + q) * 16 + (lane & 15)) * (u32)D +
              ((lane >> 4) * 8);

  const f32x4 z = {0.f, 0.f, 0.f, 0.f};
  f32x4 acc[4][4];
#pragma unroll
  for (int m = 0; m < 4; ++m)
#pragma unroll
    for (int n = 0; n < 4; ++n) acc[m][n] = z;

  const int wr = wid >> 1, wc = wid & 1;

  auto stage = [&](int buf, int kk) {
    u16* dst = ((wid < 2) ? sA[buf] : sB[buf]) + fq0 * 512;
#pragma unroll
    for (int q = 0; q < 4; ++q)
      __builtin_amdgcn_global_load_lds((const AS1 void*)(e + goff[q] + kk),
                                       (AS3 void*)(dst + q * 512), 16, 0, 0);
  };
  auto compute = [&](int buf) {
    bf16x8 a[4], b[4];
#pragma unroll
    for (int m = 0; m < 4; ++m)
      a[m] = *(const bf16x8*)&sA[buf][(wr * 4 + m) * 512 + lane * 8];
#pragma unroll
    for (int n = 0; n < 4; ++n)
      b[n] = *(const bf16x8*)&sB[buf][(wc * 4 + n) * 512 + lane * 8];
#pragma unroll
    for (int m = 0; m < 4; ++m)
#pragma unroll
      for (int n = 0; n < 4; ++n)
        acc[m][n] =
            __builtin_amdgcn_mfma_f32_16x16x32_bf16(a[m], b[n], acc[m][n], 0, 0, 0);
  };

  // prologue: stage K-step 0 into buf 0
  stage(0, 0);
  __syncthreads();

  // 2-phase main loop: prefetch t+1 into buf^1, compute buf, barrier.
#pragma unroll 2
  for (int t = 0; t < 15; ++t) {
    const int cur = t & 1;
    stage(cur ^ 1, (t + 1) * 32);
    compute(cur);
    __syncthreads();
  }
  compute(1);  // t=15, no prefetch (avoids OOB read past e)

  // Loss epilogue. C/D map (m89-verified): col = lane&15, row = (lane>>4)*4+reg.
  const float C0 = 64.0f * 0.35f;
  float lsum = 0.f;
  const int rb = i0 + wr * 64, cb = j0 + wc * 64;
#pragma unroll
  for (int m = 0; m < 4; ++m) {
    const int gi0 = rb + m * 16 + (lane >> 4) * 4;
#pragma unroll
    for (int n = 0; n < 4; ++n) {
      const int gj = cb + n * 16 + (lane & 15);
      const int lj = labels[gj];
#pragma unroll
      for (int r = 0; r < 4; ++r) {
        const int li = labels[gi0 + r];
        float s = acc[m][n][r];
        float sg = (li == lj) ? s : -s;
        float x = fmaf(-64.0f, sg, C0);  // -SCALE*(signed - MARGIN)
        float ax = fabsf(x);
        lsum += fmaxf(x, 0.f) + __logf(1.0f + __expf(-ax));
      }
    }
  }

#pragma unroll
  for (int o = 32; o >= 1; o >>= 1) lsum += __shfl_xor(lsum, o, 64);
  if (lane == 0) swred[wid] = lsum;
  __syncthreads();
  if (tid == 0) {
    float t = swred[0] + swred[1] + swred[2] + swred[3];
    partials[blockIdx.x] = (I == J) ? t : 2.0f * t;  // off-diag counts twice
  }
}

__global__ __launch_bounds__(256) void reduce_k(const float* __restrict__ partials,
                                                int n, float* __restrict__ out,
                                                double invNN) {
  double s = 0.0;
  for (int i = threadIdx.x; i < n; i += 256) s += (double)partials[i];
#pragma unroll
  for (int o = 32; o >= 1; o >>= 1) s += __shfl_xor(s, o, 64);
  __shared__ double sd[4];
  const int wid = threadIdx.x >> 6, lane = threadIdx.x & 63;
  if (lane == 0) sd[wid] = s;
  __syncthreads();
  if (threadIdx.x == 0) out[0] = (float)((sd[0] + sd[1] + sd[2] + sd[3]) * invNN);
}

extern "C" void kernel_launch(void* const* d_in, const int* in_sizes, int n_in,
                              void* d_out, int out_size, void* d_ws, size_t ws_size,
                              hipStream_t stream) {
  const float* emb = (const float*)d_in[0];
  const int* labels = (const int*)d_in[1];
  float* out = (float*)d_out;

  const int N = in_sizes[1];             // 8192
  const int D = in_sizes[0] / N;         // 512
  const int NT = N / 128;                // 64
  const int nTiles = NT * (NT + 1) / 2;  // 2080

  u16* e = (u16*)d_ws;
  float* partials = (float*)(e + (size_t)N * D);

  norm_bf16_k<<<N / 4, 256, 0, stream>>>(emb, e, N, D);
  gram_loss_k<<<nTiles, 256, 0, stream>>>(e, labels, partials, N, D, NT);
  reduce_k<<<1, 256, 0, stream>>>(partials, nTiles, out,
                                  1.0 / ((double)N * (double)N));
}

// Round 6
// 143.359 us; speedup vs baseline: 1.6380x; 1.0162x over previous
//
#include <hip/hip_runtime.h>

// CircleLoss on MI355X: mean(log1p(exp(-64*(sim*(2*pos-1) - 0.35*64))))
// over the 8192x8192 cosine-sim Gram matrix.
//
// R6 design (from R5 counters: latency-bound, 5100 cyc/K-step = naked load
// latency at every __syncthreads vmcnt(0) drain; FETCH 77MB = 9x overfetch):
//   k1: row-norm -> bf16
//   k2: upper-tri 128x128 Gram tiles, 3-deep LDS pipeline with COUNTED
//       vmcnt (never 0 mid-loop) + raw s_barrier (T3/T4), XCD-swizzled
//       tile order (T1), fused softplus epilogue
//   k3: deterministic final reduction
//
// ws: [e: N*D u16 bf16 (8.4 MB)][partials: NT*(NT+1)/2 float]

typedef unsigned short u16;
typedef unsigned int u32;
typedef __attribute__((ext_vector_type(4))) float f32x4;
typedef __attribute__((ext_vector_type(8))) short bf16x8;
typedef __attribute__((ext_vector_type(8))) u16 u16x8;

#define AS1 __attribute__((address_space(1)))
#define AS3 __attribute__((address_space(3)))

// One wave per row (D = 512 = 64 lanes * 8). 1/max(||x||,eps), bf16 RNE out.
__global__ __launch_bounds__(256) void norm_bf16_k(
    const float* __restrict__ emb, u16* __restrict__ e, int N, int D) {
  const int wid = threadIdx.x >> 6, lane = threadIdx.x & 63;
  const int row = blockIdx.x * 4 + wid;
  if (row >= N) return;
  const float* p = emb + (size_t)row * D + lane * 8;
  f32x4 a = *(const f32x4*)p;
  f32x4 b = *(const f32x4*)(p + 4);
  float ss = 0.f;
#pragma unroll
  for (int i = 0; i < 4; ++i) ss += a[i] * a[i] + b[i] * b[i];
#pragma unroll
  for (int o = 32; o >= 1; o >>= 1) ss += __shfl_xor(ss, o, 64);
  const float inv = 1.0f / fmaxf(sqrtf(ss), 1e-8f);
  u16x8 hv;
#pragma unroll
  for (int i = 0; i < 8; ++i) {
    float x = (i < 4 ? a[i] : b[i - 4]) * inv;
    u32 u = __float_as_uint(x);
    u += 0x7FFFu + ((u >> 16) & 1u);  // RNE to bf16
    hv[i] = (u16)(u >> 16);
  }
  *(u16x8*)(e + (size_t)row * D + lane * 8) = hv;
}

// Upper-tri tile (I<=J). 4 waves, 2x2 wave grid, 64x64 quadrant each =
// 4x4 fragments of mfma_f32_16x16x32_bf16.
//
// LDS: fragment-ready lane-linear (frag = 1024B, lane l holds 16B at l*16,
// gathered from global row l&15, k-octet l>>4); gload_lds lane-linear write
// == ds_read_b128 fragment read, identical gather on A and B (any within-
// octet k-permutation cancels in A.B^T). Conflict-free (R3/R5: 0 conflicts).
//
// Pipeline: 3 buffers; stage k0..k2 in prologue; per step:
//   s_waitcnt vmcnt(8)   <- my 4 loads for buf[cur] retired (2 newer stages
//                           stay in flight ACROSS the barrier - T4)
//   s_barrier            <- buf[cur] published to all waves
//   compute(cur)         <- 8 ds_read_b128 + 16 MFMA
//   s_barrier            <- all waves done reading buf[cur]
//   stage(cur, t+3)      <- refill just-consumed buffer
// Tail steps use vmcnt(4)/vmcnt(0). Fully unrolled: literal buffer indices
// and vmcnt immediates; "memory" clobbers stop LDS-read hoisting/GVN.
__global__ __launch_bounds__(256, 3) void gram_loss_k(
    const u16* __restrict__ e, const int* __restrict__ labels,
    float* __restrict__ partials, int N, int D, int NT, int nwg) {
  __shared__ __attribute__((aligned(16))) u16 sA[3][8 * 512];
  __shared__ __attribute__((aligned(16))) u16 sB[3][8 * 512];
  __shared__ float swred[4];

  const int tid = threadIdx.x, wid = tid >> 6, lane = tid & 63;

  // T1: bijective XCD swizzle (m204): contiguous tile-chunk per XCD so
  // same-I blocks (sharing the A panel) co-locate on one XCD's L2.
  const int q8 = nwg >> 3, r8 = nwg & 7;
  const int x = blockIdx.x & 7, p = blockIdx.x >> 3;
  const int bid = (x < r8 ? x * (q8 + 1) : r8 * (q8 + 1) + (x - r8) * q8) + p;

  // tile-index -> upper-triangular (I, J), I <= J
  int I = 0, rem = bid, rl = NT;
  while (rem >= rl) { rem -= rl; ++I; --rl; }
  const int J = I + rem;
  const int i0 = I * 128, j0 = J * 128;

  // Staging: wave 0 -> A frags 0-3, wave 1 -> A frags 4-7,
  //          wave 2 -> B frags 0-3, wave 3 -> B frags 4-7.
  const int rbase = (wid < 2) ? i0 : j0;
  const int fq0 = (wid & 1) * 4;
  u32 goff[4];
#pragma unroll
  for (int qq = 0; qq < 4; ++qq)
    goff[qq] = (u32)(rbase + (fq0 + qq) * 16 + (lane & 15)) * (u32)D +
               ((lane >> 4) * 8);

  const f32x4 z = {0.f, 0.f, 0.f, 0.f};
  f32x4 acc[4][4];
#pragma unroll
  for (int m = 0; m < 4; ++m)
#pragma unroll
    for (int n = 0; n < 4; ++n) acc[m][n] = z;

  const int wr = wid >> 1, wc = wid & 1;

  auto stage = [&](int buf, int kk) {
    u16* dst = ((wid < 2) ? sA[buf] : sB[buf]) + fq0 * 512;
#pragma unroll
    for (int qq = 0; qq < 4; ++qq)
      __builtin_amdgcn_global_load_lds((const AS1 void*)(e + goff[qq] + kk),
                                       (AS3 void*)(dst + qq * 512), 16, 0, 0);
  };
  auto compute = [&](int buf) {
    bf16x8 a[4], b[4];
#pragma unroll
    for (int m = 0; m < 4; ++m)
      a[m] = *(const bf16x8*)&sA[buf][(wr * 4 + m) * 512 + lane * 8];
#pragma unroll
    for (int n = 0; n < 4; ++n)
      b[n] = *(const bf16x8*)&sB[buf][(wc * 4 + n) * 512 + lane * 8];
#pragma unroll
    for (int m = 0; m < 4; ++m)
#pragma unroll
      for (int n = 0; n < 4; ++n)
        acc[m][n] =
            __builtin_amdgcn_mfma_f32_16x16x32_bf16(a[m], b[n], acc[m][n], 0, 0, 0);
  };

  // prologue: 3 K-steps in flight (12 loads/wave)
  stage(0, 0);
  stage(1, 32);
  stage(2, 64);

#define STEP(T, VM)                                          \
  asm volatile("s_waitcnt vmcnt(" #VM ")" ::: "memory");     \
  __builtin_amdgcn_s_barrier();                              \
  asm volatile("" ::: "memory");                             \
  compute((T) % 3);                                          \
  __builtin_amdgcn_s_barrier();                              \
  if ((T) + 3 < 16) stage((T) % 3, ((T) + 3) * 32);

  STEP(0, 8)  STEP(1, 8)  STEP(2, 8)  STEP(3, 8)
  STEP(4, 8)  STEP(5, 8)  STEP(6, 8)  STEP(7, 8)
  STEP(8, 8)  STEP(9, 8)  STEP(10, 8) STEP(11, 8)
  STEP(12, 8) STEP(13, 8) STEP(14, 4) STEP(15, 0)
#undef STEP

  // Loss epilogue. C/D map (m89-verified): col = lane&15, row = (lane>>4)*4+reg.
  const float C0 = 64.0f * 0.35f;
  float lsum = 0.f;
  const int rb = i0 + wr * 64, cb = j0 + wc * 64;
#pragma unroll
  for (int m = 0; m < 4; ++m) {
    const int gi0 = rb + m * 16 + (lane >> 4) * 4;
#pragma unroll
    for (int n = 0; n < 4; ++n) {
      const int gj = cb + n * 16 + (lane & 15);
      const int lj = labels[gj];
#pragma unroll
      for (int r = 0; r < 4; ++r) {
        const int li = labels[gi0 + r];
        float s = acc[m][n][r];
        float sg = (li == lj) ? s : -s;
        float xv = fmaf(-64.0f, sg, C0);  // -SCALE*(signed - MARGIN)
        float ax = fabsf(xv);
        lsum += fmaxf(xv, 0.f) + __logf(1.0f + __expf(-ax));
      }
    }
  }

#pragma unroll
  for (int o = 32; o >= 1; o >>= 1) lsum += __shfl_xor(lsum, o, 64);
  if (lane == 0) swred[wid] = lsum;
  __syncthreads();
  if (tid == 0) {
    float t = swred[0] + swred[1] + swred[2] + swred[3];
    partials[bid] = (I == J) ? t : 2.0f * t;  // off-diag counts twice
  }
}

__global__ __launch_bounds__(256) void reduce_k(const float* __restrict__ partials,
                                                int n, float* __restrict__ out,
                                                double invNN) {
  double s = 0.0;
  for (int i = threadIdx.x; i < n; i += 256) s += (double)partials[i];
#pragma unroll
  for (int o = 32; o >= 1; o >>= 1) s += __shfl_xor(s, o, 64);
  __shared__ double sd[4];
  const int wid = threadIdx.x >> 6, lane = threadIdx.x & 63;
  if (lane == 0) sd[wid] = s;
  __syncthreads();
  if (threadIdx.x == 0) out[0] = (float)((sd[0] + sd[1] + sd[2] + sd[3]) * invNN);
}

extern "C" void kernel_launch(void* const* d_in, const int* in_sizes, int n_in,
                              void* d_out, int out_size, void* d_ws, size_t ws_size,
                              hipStream_t stream) {
  const float* emb = (const float*)d_in[0];
  const int* labels = (const int*)d_in[1];
  float* out = (float*)d_out;

  const int N = in_sizes[1];             // 8192
  const int D = in_sizes[0] / N;         // 512
  const int NT = N / 128;                // 64
  const int nTiles = NT * (NT + 1) / 2;  // 2080

  u16* e = (u16*)d_ws;
  float* partials = (float*)(e + (size_t)N * D);

  norm_bf16_k<<<N / 4, 256, 0, stream>>>(emb, e, N, D);
  gram_loss_k<<<nTiles, 256, 0, stream>>>(e, labels, partials, N, D, NT, nTiles);
  reduce_k<<<1, 256, 0, stream>>>(partials, nTiles, out,
                                  1.0 / ((double)N * (double)N));
}